// Round 19
// baseline (43.046 us; speedup 1.0000x reference)
//
#include <hip/hip_runtime.h>
#include <hip/hip_bf16.h>

// SimpleUnsharedPatchScorer — register-run reduction, h-split blocks, bf16 wlay,
// NON-TEMPORAL x loads (via ext_vector_type alias; HIP_vector_type rejected by builtin).
// t = i*9408 + j*588 + c*196 + h*14 + w  (i,j in [0,16), c in [0,3), h,w in [0,14))
// value at t: x[b, c, 16h+i, 16w+j];  out bin p = t/768.
// Ledger: R10/R11 lane map neutral; R12-R14 pairing regressed; R17 bf16 weights WIN
// (35.9->33.2, weight bytes on critical path). R18: x has ZERO reuse -> nt loads keep
// the x stream from evicting L2-resident wlay (1.2MB working set/XCD vs 19MB x/XCD).

#define NPATCH 196
#define NF4IMG 37632     // float4s per image = 150528/4
#define BSTR   197       // LDS bin row stride

typedef float v4f __attribute__((ext_vector_type(4)));

__device__ __forceinline__ float bf2f(unsigned short s) {
    return __uint_as_float((unsigned int)s << 16);
}

// prep: bid<147: wlay[(tile*14+w)*256 + i*16 + jj] = bf16(weight[t]) (coalesced read);
//       bid>=147: out[g] = bias[g%196] (coalesced float4 store).
__global__ __launch_bounds__(256) void prep_kernel(
    const float* __restrict__ weight,
    const float* __restrict__ bias,
    __hip_bfloat16* __restrict__ wlay,
    float* __restrict__ out)
{
    const int bid = blockIdx.x;
    if (bid < 147) {                          // 147*256*4 == 150528 weights
        const int t4 = bid * 256 + threadIdx.x;
        const float4 wv = ((const float4*)weight)[t4];
        const float wt[4] = {wv.x, wv.y, wv.z, wv.w};
        #pragma unroll
        for (int u = 0; u < 4; ++u) {
            const int t    = 4 * t4 + u;
            const int i    = t / 9408;
            const int rem  = t - i * 9408;
            const int jj   = rem / 588;
            const int rem2 = rem - jj * 588;
            const int c    = rem2 / 196;
            const int rem3 = rem2 - c * 196;
            const int h    = rem3 / 14;
            const int w    = rem3 - h * 14;
            wlay[((c * 14 + h) * 14 + w) * 256 + i * 16 + jj] = __float2bfloat16(wt[u]);
        }
    } else {                                  // 49*256*4 == 50176 == 256*196 bias-init
        const int g4 = (bid - 147) * 256 + threadIdx.x;
        const int g  = 4 * g4;
        float4 o;
        o.x = bias[(g + 0) % NPATCH];
        o.y = bias[(g + 1) % NPATCH];
        o.z = bias[(g + 2) % NPATCH];
        o.w = bias[(g + 3) % NPATCH];
        ((float4*)out)[g4] = o;
    }
}

__global__ __launch_bounds__(448) void run_kernel(
    const float* __restrict__ x,              // [256,3,224,224]
    const __hip_bfloat16* __restrict__ wlay,  // permuted bf16 weights (150528)
    float* __restrict__ out)                  // [256,196], bias pre-loaded
{
    __shared__ float bins[7 * BSTR];
    const int tid  = threadIdx.x;
    const int b    = blockIdx.x >> 1;         // image
    const int hh   = blockIdx.x & 1;          // h half
    const int wv   = tid >> 6;                // wave 0..6
    const int lane = tid & 63;
    const int i    = lane >> 2;
    const int j4   = lane & 3;                // j = 4*j4 + dj
    const int h    = hh * 7 + wv;

    for (int k = tid; k < 7 * BSTR; k += 448) bins[k] = 0.0f;
    __syncthreads();

    float* mybins = bins + wv * BSTR;

    #pragma unroll
    for (int c = 0; c < 3; ++c) {
        const int tile = c * 14 + h;
        const v4f* __restrict__ x4 = (const v4f*)x + (size_t)b * NF4IMG
                                     + c * 12544 + (16 * h + i) * 56 + j4;
        const ushort4* __restrict__ w4 = (const ushort4*)wlay + tile * 896 + i * 4 + j4;

        int p0[4], ws_[4];
        #pragma unroll
        for (int dj = 0; dj < 4; ++dj) {
            const int jj = 4 * j4 + dj;
            const int t0 = i * 9408 + jj * 588 + c * 196 + h * 14;
            p0[dj]  = t0 / 768;
            ws_[dj] = 768 * (p0[dj] + 1) - t0;   // w >= ws_ -> bin p0+1 (ws_=14 => no split)
        }

        float accA[4] = {0.f, 0.f, 0.f, 0.f};
        float accB[4] = {0.f, 0.f, 0.f, 0.f};
        #pragma unroll
        for (int w = 0; w < 14; ++w) {
            const v4f     xv  = __builtin_nontemporal_load(&x4[4 * w]);  // nt: zero-reuse stream
            const ushort4 wv_ = w4[64 * w];       // 8B: 4 bf16 weights (L2-resident)
            const float xs[4]  = {xv.x, xv.y, xv.z, xv.w};
            const float wsv[4] = {bf2f(wv_.x), bf2f(wv_.y), bf2f(wv_.z), bf2f(wv_.w)};
            #pragma unroll
            for (int dj = 0; dj < 4; ++dj) {
                const float v   = xs[dj] * wsv[dj];
                const float sel = (w < ws_[dj]) ? 1.0f : 0.0f;
                accA[dj] = fmaf(v, sel, accA[dj]);
                accB[dj] = fmaf(v, 1.0f - sel, accB[dj]);
            }
        }

        #pragma unroll
        for (int dj = 0; dj < 4; ++dj) {
            unsafeAtomicAdd(&mybins[p0[dj]], accA[dj]);          // ds_add_f32, per-wave row
            if (ws_[dj] < 14)
                unsafeAtomicAdd(&mybins[p0[dj] + 1], accB[dj]);  // rare split (~1.7%)
        }
    }
    __syncthreads();

    // 7-way tree sum, then one device atomic per (block, p): 196*512 ~= 100K total
    for (int p = tid; p < NPATCH; p += 448) {
        float s = 0.0f;
        #pragma unroll
        for (int k = 0; k < 7; ++k) s += bins[k * BSTR + p];
        unsafeAtomicAdd(&out[b * NPATCH + p], s);
    }
}

extern "C" void kernel_launch(void* const* d_in, const int* in_sizes, int n_in,
                              void* d_out, int out_size, void* d_ws, size_t ws_size,
                              hipStream_t stream) {
    const float* x      = (const float*)d_in[0];
    const float* weight = (const float*)d_in[1];
    const float* bias   = (const float*)d_in[2];
    float* out          = (float*)d_out;
    __hip_bfloat16* wlay = (__hip_bfloat16*)d_ws;   // 301056 bytes

    prep_kernel<<<196, 256, 0, stream>>>(weight, bias, wlay, out);
    run_kernel<<<512, 448, 0, stream>>>(x, wlay, out);
}

// Round 20
// 32.921 us; speedup vs baseline: 1.3076x; 1.3076x over previous
//
#include <hip/hip_runtime.h>
#include <hip/hip_bf16.h>

// SimpleUnsharedPatchScorer — register-run reduction, h-split blocks, bf16 wlay.
// (R17 champion, reverted after R19's nt-load regression.)
// t = i*9408 + j*588 + c*196 + h*14 + w  (i,j in [0,16), c in [0,3), h,w in [0,14))
// value at t: x[b, c, 16h+i, 16w+j];  out bin p = t/768.
// Final ledger: R6 LDS-atomic wall; R7 global-atomic wall (fixed R8); R10/R11 128B lane
// map neutral; R12-R14 image-pairing regressed; R17 bf16 weights WIN (35.9->33.2);
// R19 nontemporal x loads LOSE (43.0 — nt bypasses the L3 assist on the 154MB x set).
// 33.2us = ~27 run (x stream at ~fill ceiling w/ L3 assist) + ~2.3 prep + launch/tail.

#define NPATCH 196
#define NF4IMG 37632     // float4s per image = 150528/4
#define BSTR   197       // LDS bin row stride

__device__ __forceinline__ float bf2f(unsigned short s) {
    return __uint_as_float((unsigned int)s << 16);
}

// prep: bid<147: wlay[(tile*14+w)*256 + i*16 + jj] = bf16(weight[t]) (coalesced read);
//       bid>=147: out[g] = bias[g%196] (coalesced float4 store).
__global__ __launch_bounds__(256) void prep_kernel(
    const float* __restrict__ weight,
    const float* __restrict__ bias,
    __hip_bfloat16* __restrict__ wlay,
    float* __restrict__ out)
{
    const int bid = blockIdx.x;
    if (bid < 147) {                          // 147*256*4 == 150528 weights
        const int t4 = bid * 256 + threadIdx.x;
        const float4 wv = ((const float4*)weight)[t4];
        const float wt[4] = {wv.x, wv.y, wv.z, wv.w};
        #pragma unroll
        for (int u = 0; u < 4; ++u) {
            const int t    = 4 * t4 + u;
            const int i    = t / 9408;
            const int rem  = t - i * 9408;
            const int jj   = rem / 588;
            const int rem2 = rem - jj * 588;
            const int c    = rem2 / 196;
            const int rem3 = rem2 - c * 196;
            const int h    = rem3 / 14;
            const int w    = rem3 - h * 14;
            wlay[((c * 14 + h) * 14 + w) * 256 + i * 16 + jj] = __float2bfloat16(wt[u]);
        }
    } else {                                  // 49*256*4 == 50176 == 256*196 bias-init
        const int g4 = (bid - 147) * 256 + threadIdx.x;
        const int g  = 4 * g4;
        float4 o;
        o.x = bias[(g + 0) % NPATCH];
        o.y = bias[(g + 1) % NPATCH];
        o.z = bias[(g + 2) % NPATCH];
        o.w = bias[(g + 3) % NPATCH];
        ((float4*)out)[g4] = o;
    }
}

__global__ __launch_bounds__(448) void run_kernel(
    const float* __restrict__ x,              // [256,3,224,224]
    const __hip_bfloat16* __restrict__ wlay,  // permuted bf16 weights (150528)
    float* __restrict__ out)                  // [256,196], bias pre-loaded
{
    __shared__ float bins[7 * BSTR];
    const int tid  = threadIdx.x;
    const int b    = blockIdx.x >> 1;         // image
    const int hh   = blockIdx.x & 1;          // h half
    const int wv   = tid >> 6;                // wave 0..6
    const int lane = tid & 63;
    const int i    = lane >> 2;
    const int j4   = lane & 3;                // j = 4*j4 + dj
    const int h    = hh * 7 + wv;

    for (int k = tid; k < 7 * BSTR; k += 448) bins[k] = 0.0f;
    __syncthreads();

    float* mybins = bins + wv * BSTR;

    #pragma unroll
    for (int c = 0; c < 3; ++c) {
        const int tile = c * 14 + h;
        const float4* __restrict__ x4 = (const float4*)x + (size_t)b * NF4IMG
                                        + c * 12544 + (16 * h + i) * 56 + j4;
        const ushort4* __restrict__ w4 = (const ushort4*)wlay + tile * 896 + i * 4 + j4;

        int p0[4], ws_[4];
        #pragma unroll
        for (int dj = 0; dj < 4; ++dj) {
            const int jj = 4 * j4 + dj;
            const int t0 = i * 9408 + jj * 588 + c * 196 + h * 14;
            p0[dj]  = t0 / 768;
            ws_[dj] = 768 * (p0[dj] + 1) - t0;   // w >= ws_ -> bin p0+1 (ws_=14 => no split)
        }

        float accA[4] = {0.f, 0.f, 0.f, 0.f};
        float accB[4] = {0.f, 0.f, 0.f, 0.f};
        #pragma unroll
        for (int w = 0; w < 14; ++w) {
            const float4  xv  = x4[4 * w];
            const ushort4 wv_ = w4[64 * w];       // 8B: 4 bf16 weights
            const float xs[4]  = {xv.x, xv.y, xv.z, xv.w};
            const float wsv[4] = {bf2f(wv_.x), bf2f(wv_.y), bf2f(wv_.z), bf2f(wv_.w)};
            #pragma unroll
            for (int dj = 0; dj < 4; ++dj) {
                const float v   = xs[dj] * wsv[dj];
                const float sel = (w < ws_[dj]) ? 1.0f : 0.0f;
                accA[dj] = fmaf(v, sel, accA[dj]);
                accB[dj] = fmaf(v, 1.0f - sel, accB[dj]);
            }
        }

        #pragma unroll
        for (int dj = 0; dj < 4; ++dj) {
            unsafeAtomicAdd(&mybins[p0[dj]], accA[dj]);          // ds_add_f32, per-wave row
            if (ws_[dj] < 14)
                unsafeAtomicAdd(&mybins[p0[dj] + 1], accB[dj]);  // rare split (~1.7%)
        }
    }
    __syncthreads();

    // 7-way tree sum, then one device atomic per (block, p): 196*512 ~= 100K total
    for (int p = tid; p < NPATCH; p += 448) {
        float s = 0.0f;
        #pragma unroll
        for (int k = 0; k < 7; ++k) s += bins[k * BSTR + p];
        unsafeAtomicAdd(&out[b * NPATCH + p], s);
    }
}

extern "C" void kernel_launch(void* const* d_in, const int* in_sizes, int n_in,
                              void* d_out, int out_size, void* d_ws, size_t ws_size,
                              hipStream_t stream) {
    const float* x      = (const float*)d_in[0];
    const float* weight = (const float*)d_in[1];
    const float* bias   = (const float*)d_in[2];
    float* out          = (float*)d_out;
    __hip_bfloat16* wlay = (__hip_bfloat16*)d_ws;   // 301056 bytes

    prep_kernel<<<196, 256, 0, stream>>>(weight, bias, wlay, out);
    run_kernel<<<512, 448, 0, stream>>>(x, wlay, out);
}